// Round 4
// baseline (279.396 us; speedup 1.0000x reference)
//
#include <hip/hip_runtime.h>
#include <hip/hip_cooperative_groups.h>
#include <math.h>

namespace cg = cooperative_groups;

// Problem shape (from reference setup_inputs): B=4096, D=2048, C=1000, N=C+B=5096.
#define D_DIM 2048
// |approx_logit - exact_logit| bound: fp16-MFMA dot (~0.013) + 2x f16 partial
// roundings (~0.004). Candidate containment needs GAP_TAU >= true bound.
#define GAP_TAU 0.03f
#define SPLITK 2
#define MAXLIST 1024

typedef _Float16 f16;
typedef f16 f16x8 __attribute__((ext_vector_type(8)));
typedef f16 f16x4 __attribute__((ext_vector_type(4)));
typedef float f32x4 __attribute__((ext_vector_type(4)));
typedef float f32x16 __attribute__((ext_vector_type(16)));

__device__ __forceinline__ const float* support_row(int i, const float* __restrict__ W,
                                                    const float* __restrict__ z, int C) {
  return (i < C) ? (W + (size_t)i * D_DIM) : (z + (size_t)(i - C) * D_DIM);
}

// async global->LDS, 16B per lane. LDS dest = wave-uniform base + lane*16.
__device__ __forceinline__ void async_ld16(const f16* g, f16* l) {
  __builtin_amdgcn_global_load_lds((const __attribute__((address_space(1))) void*)g,
                                   (__attribute__((address_space(3))) void*)l, 16, 0, 0);
}

// ---------------------------------------------------------------------------
// prep: suph[i][:] = f16(support_row(i)) (zeros for pad rows); norms[i] = ||row||.
// One wave per row (4 rows/block), shuffle-only reduction.
// Also zeroes cls_cnt[0..C) and *repCnt (consumed after fused_stats phase A).
// ---------------------------------------------------------------------------
__global__ __launch_bounds__(256) void prep_kernel(const float* __restrict__ z,
                                                   const float* __restrict__ W,
                                                   int C, int Nsup,
                                                   f16* __restrict__ suph,
                                                   float* __restrict__ norms,
                                                   int* __restrict__ cls_cnt,
                                                   int* __restrict__ repCnt) {
  if (blockIdx.x * 256 <= (unsigned)C) {
    const int gi = blockIdx.x * 256 + threadIdx.x;
    if (gi < C) cls_cnt[gi] = 0;
    if (gi == C) *repCnt = 0;
  }
  const int wave = threadIdx.x >> 6;
  const int lane = threadIdx.x & 63;
  const int i = blockIdx.x * 4 + wave;
  f16* dst = suph + (size_t)i * D_DIM;
  if (i >= Nsup) {
    f16x8 zz = {0, 0, 0, 0, 0, 0, 0, 0};
#pragma unroll
    for (int p = 0; p < 4; p++) *(f16x8*)(dst + p * 512 + lane * 8) = zz;
    return;
  }
  const float* src = support_row(i, W, z, C);
  float ss = 0.f;
#pragma unroll
  for (int p = 0; p < 4; p++) {
    const int off = p * 512 + lane * 8;
    const float4 a = *(const float4*)(src + off);
    const float4 b = *(const float4*)(src + off + 4);
    f16x8 v;
    v[0] = (f16)a.x; v[1] = (f16)a.y; v[2] = (f16)a.z; v[3] = (f16)a.w;
    v[4] = (f16)b.x; v[5] = (f16)b.y; v[6] = (f16)b.z; v[7] = (f16)b.w;
    *(f16x8*)(dst + off) = v;
    ss = fmaf(a.x, a.x, ss); ss = fmaf(a.y, a.y, ss);
    ss = fmaf(a.z, a.z, ss); ss = fmaf(a.w, a.w, ss);
    ss = fmaf(b.x, b.x, ss); ss = fmaf(b.y, b.y, ss);
    ss = fmaf(b.z, b.z, ss); ss = fmaf(b.w, b.w, ss);
  }
#pragma unroll
  for (int s = 1; s < 64; s <<= 1) ss += __shfl_xor(ss, s);
  if (lane == 0) norms[i] = sqrtf(ss);
}

// ---------------------------------------------------------------------------
// fp16 MFMA GEMM, split-K=2, f16 partials, BK=64, XCD-pinned work mapping.
// 128x128 tile, 256 thr = 4 waves (2x2), wave = 64x64 = 2x2 MFMA 32x32x16,
// 4 k-steps of K=16 per BK=64 iter (16 iters at Ks=1024). LDS 32 KB.
// Swizzle: physical chunk p = g ^ (row&7) -> conflict-free ds_read_b128.
// C/D 32x32 layout: col = lane&31, row = (reg&3) + 8*(reg>>2) + 4*(lane>>5).
// ---------------------------------------------------------------------------
#define TM 128
#define TN 128
#define BK 64

__global__ __launch_bounds__(256) void gemm_f16(const f16* __restrict__ A,
                                                const f16* __restrict__ B,
                                                f16* __restrict__ P,
                                                int K, int Ks, long partStride, int ldc,
                                                int txPerXcd) {
  __shared__ __align__(16) f16 As[TM * BK];  // 16 KB
  __shared__ __align__(16) f16 Bs[TN * BK];  // 16 KB

  const int l = blockIdx.x;
  const int xcd = l & 7;
  const int slot = l >> 3;
  const int tx = xcd + 8 * (slot % txPerXcd);
  const int rest = slot / txPerXcd;        // 0..15
  const int ty = rest & 7;
  const int kz = rest >> 3;
  const int row0 = tx * TM;
  const int col0 = ty * TN;
  const int kbase = kz * Ks;

  const int tid = threadIdx.x;
  const int wave = tid >> 6;
  const int lane = tid & 63;
  const int lr32 = lane & 31;    // row within 32-block (A) / col (B, C/D)
  const int half = lane >> 5;    // k-chunk half selector
  const int wr = (wave >> 1) * 64;
  const int wc = (wave & 1) * 64;

  // staging: 1024 16B-chunks per tile -> 4 instr/thread for A, 4 for B.
  // chunk id i = (row<<3)|p; source global chunk g = p ^ (row&7).
  const f16* ag[4];
  const f16* bg[4];
  f16* al[4];
  f16* bl[4];
#pragma unroll
  for (int s = 0; s < 4; s++) {
    const int i = (wave * 4 + s) * 64 + lane;   // == LDS chunk id (staging contract)
    const int row = i >> 3;
    const int cg = (i & 7) ^ (row & 7);
    ag[s] = A + (size_t)(row0 + row) * K + kbase + cg * 8;
    bg[s] = B + (size_t)(col0 + row) * K + kbase + cg * 8;
    al[s] = As + (wave * 4 + s) * 512;
    bl[s] = Bs + (wave * 4 + s) * 512;
  }

  // fragment offsets: for k-step s (K=16), lane reads global chunk
  // (s*2 + half) of row r at physical chunk ((s*2+half) ^ (r&7)).
  int aoff[2][4], boff[2][4];
#pragma unroll
  for (int b = 0; b < 2; b++) {
#pragma unroll
    for (int s = 0; s < 4; s++) {
      const int ra = wr + b * 32 + lr32;
      aoff[b][s] = ra * 64 + (((s * 2 + half) ^ (ra & 7)) << 3);
      const int rb = wc + b * 32 + lr32;
      boff[b][s] = rb * 64 + (((s * 2 + half) ^ (rb & 7)) << 3);
    }
  }

  f32x16 acc[2][2];
#pragma unroll
  for (int i = 0; i < 2; i++)
#pragma unroll
    for (int j = 0; j < 2; j++)
#pragma unroll
      for (int r = 0; r < 16; r++) acc[i][j][r] = 0.f;

  for (int k0 = 0; k0 < Ks; k0 += BK) {
#pragma unroll
    for (int s = 0; s < 4; s++) {
      async_ld16(ag[s] + k0, al[s]);
      async_ld16(bg[s] + k0, bl[s]);
    }
    __syncthreads();

#pragma unroll
    for (int s = 0; s < 4; s++) {
      f16x8 af[2], bf[2];
      af[0] = *(const f16x8*)(As + aoff[0][s]);
      af[1] = *(const f16x8*)(As + aoff[1][s]);
      bf[0] = *(const f16x8*)(Bs + boff[0][s]);
      bf[1] = *(const f16x8*)(Bs + boff[1][s]);
      acc[0][0] = __builtin_amdgcn_mfma_f32_32x32x16_f16(af[0], bf[0], acc[0][0], 0, 0, 0);
      acc[0][1] = __builtin_amdgcn_mfma_f32_32x32x16_f16(af[0], bf[1], acc[0][1], 0, 0, 0);
      acc[1][0] = __builtin_amdgcn_mfma_f32_32x32x16_f16(af[1], bf[0], acc[1][0], 0, 0, 0);
      acc[1][1] = __builtin_amdgcn_mfma_f32_32x32x16_f16(af[1], bf[1], acc[1][1], 0, 0, 0);
    }
    __syncthreads();
  }

  f16* out = P + (size_t)kz * partStride;
#pragma unroll
  for (int bi = 0; bi < 2; bi++)
#pragma unroll
    for (int reg = 0; reg < 16; reg++) {
      const int r = row0 + wr + bi * 32 + (reg & 3) + ((reg >> 2) << 3) + (half << 2);
#pragma unroll
      for (int bj = 0; bj < 2; bj++) {
        const int c = col0 + wc + bj * 32 + lr32;
        out[(size_t)r * ldc + c] = (f16)acc[bi][bj][reg];
      }
    }
}

// ---------------------------------------------------------------------------
// fused_stats (COOPERATIVE, grid 512): three phases with grid-wide syncs,
// replacing the row_stats / repair / accum launch chain.
//  A) wave-per-row split-K merge + argmax/entropy; ambiguous -> repair list,
//     resolved -> class buckets. (verbatim round-3 arithmetic)
//  B) exact fp32 repair of ambiguous rows, block-per-row grid-stride
//     (dot order bitwise == round-3 repair_kernel).
//  C) per-class gather/select/accumulate/normalize -> wh. (verbatim)
// ---------------------------------------------------------------------------
__global__ __launch_bounds__(256) void fused_stats(
    const f16* __restrict__ P, long partStride, int ldp, int Cc, int Nsup, int Npad,
    const float* __restrict__ z, const float* __restrict__ W,
    float* __restrict__ ent, int* __restrict__ repCnt, int* __restrict__ repRows,
    int* __restrict__ cls_cnt, int* __restrict__ cls_idx,
    const float* __restrict__ norms, const int* __restrict__ Kp,
    f16* __restrict__ wh) {
  cg::grid_group grid = cg::this_grid();
  const int t = threadIdx.x;
  const int wave = t >> 6;
  const int lane = t & 63;

  __shared__ float sm1[4], sm2[4];
  __shared__ float bc[2];
  __shared__ int cand[64];
  __shared__ int ncand;
  __shared__ float red[256];
  __shared__ int slist[MAXLIST];
  __shared__ unsigned char sel[MAXLIST];

  // ---------------- Phase A: per-row stats (one wave per row) ----------------
  for (int r0 = blockIdx.x * 4; r0 < Nsup; r0 += gridDim.x * 4) {
    const int r = r0 + wave;
    if (r < Nsup) {
      const f16* base = P + (size_t)r * ldp + lane * 8;
      const f16x8 p0 = *(const f16x8*)(base);
      const f16x8 p1 = *(const f16x8*)(base + 512);
      const f16x8 q0 = *(const f16x8*)(base + partStride);
      const f16x8 q1 = *(const f16x8*)(base + partStride + 512);

      float v[16];
#pragma unroll
      for (int k = 0; k < 8; k++) v[k] = (float)p0[k] + (float)q0[k];
#pragma unroll
      for (int k = 0; k < 8; k++) v[8 + k] = (float)p1[k] + (float)q1[k];

      const int cbase = lane * 8;
#pragma unroll
      for (int k = 0; k < 16; k++) {
        const int col = (k < 8) ? (cbase + k) : (512 + cbase + k - 8);
        if (col >= Cc) v[k] = -3.0e38f;
      }

      // per-lane top-2 (+ lowest argmax idx; ascending col order within lane)
      float m1 = -3.0e38f, m2 = -3.0e38f;
      int i1 = 0x7fffffff;
#pragma unroll
      for (int k = 0; k < 16; k++) {
        const int col = (k < 8) ? (cbase + k) : (512 + cbase + k - 8);
        const float x = v[k];
        if (x > m1) { m2 = m1; m1 = x; i1 = col; }
        else if (x > m2) { m2 = x; }   // x==m1 lands here -> m2=m1 (gap 0)
      }
      // butterfly merge: all lanes converge to global (m1, m2, lowest i1)
#pragma unroll
      for (int s = 1; s < 64; s <<= 1) {
        const float om1 = __shfl_xor(m1, s);
        const float om2 = __shfl_xor(m2, s);
        const int oi1 = __shfl_xor(i1, s);
        if (om1 > m1) { m2 = fmaxf(m1, om2); m1 = om1; i1 = oi1; }
        else if (om1 < m1) { m2 = fmaxf(m2, om1); }
        else { i1 = min(i1, oi1); m2 = m1; }
      }

      // entropy rel. m1 (consumed only if a class exceeds K members)
      float s1 = 0.f, s2 = 0.f;
#pragma unroll
      for (int k = 0; k < 16; k++) {
        const int col = (k < 8) ? (cbase + k) : (512 + cbase + k - 8);
        if (col < Cc) {
          const float d = v[k] - m1;
          const float e = __expf(d);
          s1 += e;
          s2 = fmaf(d, e, s2);
        }
      }
#pragma unroll
      for (int s = 1; s < 64; s <<= 1) {
        s1 += __shfl_xor(s1, s);
        s2 += __shfl_xor(s2, s);
      }

      if (lane == 0) {
        ent[r] = logf(s1) - s2 / s1;
        if (m1 - m2 <= 2.0f * GAP_TAU) {
          const int p = atomicAdd(repCnt, 1);
          if (p < Nsup) repRows[p] = r;
        } else {
          const int p = atomicAdd(&cls_cnt[i1], 1);
          if (p < MAXLIST) cls_idx[(size_t)i1 * MAXLIST + p] = r;
        }
      }
    }
  }

  grid.sync();

  // ---------------- Phase B: exact repair of ambiguous rows ----------------
  const int nrep = *repCnt;
  for (int q = blockIdx.x; q < nrep; q += gridDim.x) {
    const int r = repRows[q];
    const int c0 = t * 4;
    float v[4] = {0.f, 0.f, 0.f, 0.f};
#pragma unroll
    for (int kz = 0; kz < SPLITK; kz++) {
      const f16x4 p = *(const f16x4*)(P + (size_t)kz * partStride + (size_t)r * ldp + c0);
#pragma unroll
      for (int k = 0; k < 4; k++) v[k] += (float)p[k];
    }
#pragma unroll
    for (int k = 0; k < 4; k++)
      if (c0 + k >= Cc) v[k] = -3.0e38f;

    // top-2 values only (indices resolved by exact dots below)
    float m1 = -3.0e38f, m2 = -3.0e38f;
#pragma unroll
    for (int k = 0; k < 4; k++) {
      const float x = v[k];
      if (x > m1) { m2 = m1; m1 = x; }
      else if (x > m2) { m2 = x; }
    }
#pragma unroll
    for (int s = 1; s < 64; s <<= 1) {
      const float om1 = __shfl_xor(m1, s);
      const float om2 = __shfl_xor(m2, s);
      if (om1 > m1) { m2 = fmaxf(m1, om2); m1 = om1; }
      else if (om1 < m1) { m2 = fmaxf(m2, om1); }
      else { m2 = m1; }
    }
    if (lane == 0) { sm1[wave] = m1; sm2[wave] = m2; }
    __syncthreads();
    if (t == 0) {
      float M1 = sm1[0], M2 = sm2[0];
#pragma unroll
      for (int w = 1; w < 4; w++) {
        const float o1 = sm1[w], o2 = sm2[w];
        if (o1 > M1) { M2 = fmaxf(M1, o2); M1 = o1; }
        else if (o1 < M1) { M2 = fmaxf(M2, o1); }
        else { M2 = M1; }
      }
      bc[0] = M1; bc[1] = M2;
      ncand = 0;
    }
    __syncthreads();
    const float M1 = bc[0];
    const float thresh = M1 - 2.0f * GAP_TAU;
#pragma unroll
    for (int k = 0; k < 4; k++) {
      if (c0 + k < Cc && v[k] >= thresh) {
        const int p = atomicAdd(&ncand, 1);
        if (p < 64) cand[p] = c0 + k;
      }
    }
    __syncthreads();
    const bool overflow = (ncand > 64);
    const int nc = overflow ? Cc : ncand;
    const float* srow = support_row(r, W, z, Cc);
    float best = -3.0e38f;
    int bi = 0x7fffffff;
    for (int j = 0; j < nc; j++) {
      const int c = overflow ? j : cand[j];
      const float* wrow = W + (size_t)c * D_DIM;
      float s = 0.f;
      for (int d = t; d < D_DIM; d += 256) s = fmaf(srow[d], wrow[d], s);
      red[t] = s;
      __syncthreads();
      for (int k = 128; k > 0; k >>= 1) {
        if (t < k) red[t] += red[t + k];
        __syncthreads();
      }
      const float val = red[0];
      __syncthreads();
      if (val > best || (val == best && c < bi)) { best = val; bi = c; }
    }
    if (t == 0) {
      const int p = atomicAdd(&cls_cnt[bi], 1);
      if (p < MAXLIST) cls_idx[(size_t)bi * MAXLIST + p] = r;
    }
    __syncthreads();   // shared reuse across q iterations
  }

  grid.sync();

  // ---------------- Phase C: per-class accumulate/normalize ----------------
  for (int c = blockIdx.x; c < Npad; c += gridDim.x) {
    f16* dst = wh + (size_t)c * D_DIM + t * 8;
    if (c >= Cc) {
      f16x8 zz = {0, 0, 0, 0, 0, 0, 0, 0};
      *(f16x8*)dst = zz;
      continue;
    }
    const int cnt = cls_cnt[c];
    const int n = min(cnt, MAXLIST);
    const int* list = cls_idx + (size_t)c * MAXLIST;
    for (int j = t; j < n; j += 256) slist[j] = list[j];
    __syncthreads();
    const int K = *Kp;
    const bool all = (cnt <= K);
    if (!all) {
      for (int j = t; j < n; j += 256) {
        const int si = slist[j];
        const float ei = ent[si];
        int rank = 0;
        for (int l = 0; l < n; l++) {
          const int sl = slist[l];
          const float el = ent[sl];
          rank += (el < ei || (el == ei && sl < si)) ? 1 : 0;
        }
        sel[j] = (rank < K) ? 1 : 0;
      }
      __syncthreads();
    }

    float a[8];
#pragma unroll
    for (int q = 0; q < 8; q++) a[q] = 0.f;
    for (int j = 0; j < n; j++) {
      if (!all && !sel[j]) continue;
      const int si = slist[j];
      const float* row = support_row(si, W, z, Cc) + t * 8;
      const float inv = 1.0f / fmaxf(norms[si], 1e-12f);
      const float4 p0 = *(const float4*)row;
      const float4 p1 = *(const float4*)(row + 4);
      a[0] = fmaf(p0.x, inv, a[0]); a[1] = fmaf(p0.y, inv, a[1]);
      a[2] = fmaf(p0.z, inv, a[2]); a[3] = fmaf(p0.w, inv, a[3]);
      a[4] = fmaf(p1.x, inv, a[4]); a[5] = fmaf(p1.y, inv, a[5]);
      a[6] = fmaf(p1.z, inv, a[6]); a[7] = fmaf(p1.w, inv, a[7]);
    }

    float ss = 0.f;
#pragma unroll
    for (int q = 0; q < 8; q++) ss = fmaf(a[q], a[q], ss);
    red[t] = ss;
    __syncthreads();
    for (int k = 128; k > 0; k >>= 1) {
      if (t < k) red[t] += red[t + k];
      __syncthreads();
    }
    const float invn = 1.0f / fmaxf(sqrtf(red[0]), 1e-12f);
    f16x8 o;
#pragma unroll
    for (int q = 0; q < 8; q++) o[q] = (f16)(a[q] * invn);
    *(f16x8*)dst = o;
    __syncthreads();   // red/slist reuse across c iterations
  }
}

// ---------------------------------------------------------------------------
// reduce_out: out[r][c] = sum of 2 f16 partials, c < Ncols. Two rows per
// block; thread owns 8 cols (f16x8 loads, 2x float4 store).
// ---------------------------------------------------------------------------
__global__ __launch_bounds__(256) void reduce_out(const f16* __restrict__ Q,
                                                  long partStride, int ldq,
                                                  float* __restrict__ out, int Ncols) {
  const int r = blockIdx.x * 2 + (threadIdx.x >> 7);
  const int c0 = (threadIdx.x & 127) * 8;
  const f16* base = Q + (size_t)r * ldq + c0;
  const f16x8 p = *(const f16x8*)(base);
  const f16x8 q = *(const f16x8*)(base + partStride);
  float v[8];
#pragma unroll
  for (int k = 0; k < 8; k++) v[k] = (float)p[k] + (float)q[k];
  float* o = out + (size_t)r * Ncols + c0;
  if (c0 + 8 <= Ncols) {
    *(float4*)(o) = make_float4(v[0], v[1], v[2], v[3]);
    *(float4*)(o + 4) = make_float4(v[4], v[5], v[6], v[7]);
  } else {
#pragma unroll
    for (int k = 0; k < 8; k++)
      if (c0 + k < Ncols) o[k] = v[k];
  }
}

// ---------------------------------------------------------------------------
// Launch
// ---------------------------------------------------------------------------
extern "C" void kernel_launch(void* const* d_in, const int* in_sizes, int n_in,
                              void* d_out, int out_size, void* d_ws, size_t ws_size,
                              hipStream_t stream) {
  const float* z = (const float*)d_in[0];
  const float* W = (const float*)d_in[1];
  const int* Kp = (const int*)d_in[2];

  const int D = D_DIM;
  const int B = in_sizes[0] / D;   // 4096
  const int C = in_sizes[1] / D;   // 1000
  const int Nsup = C + B;          // 5096
  const int Mpad = (Nsup + TM - 1) / TM * TM;  // 5120
  const int Npad = (C + TN - 1) / TN * TN;     // 1024

  char* ws = (char*)d_ws;
  size_t off = 0;
  auto alloc = [&](size_t bytes) -> void* {
    void* p = ws + off;
    off += (bytes + 255) & ~(size_t)255;
    return p;
  };

  const long pStride1 = (long)Mpad * Npad;   // f16 elems per partial (gemm1)
  const long pStride2 = (long)B * Npad;      // f16 elems per partial (gemm2)

  f16*   suph   = (f16*)alloc((size_t)Mpad * D * sizeof(f16));            // ~21.0 MB
  f16*   wh     = (f16*)alloc((size_t)Npad * D * sizeof(f16));            // ~4.2 MB
  f16*   P      = (f16*)alloc((size_t)SPLITK * pStride1 * sizeof(f16));   // ~21.0 MB
  float* ent    = (float*)alloc((size_t)Nsup * sizeof(float));
  float* norms  = (float*)alloc((size_t)Nsup * sizeof(float));
  int*   cls_cnt = (int*)alloc((size_t)C * sizeof(int));
  int*   cls_idx = (int*)alloc((size_t)C * MAXLIST * sizeof(int));        // ~4.1 MB
  int*   repCnt = (int*)alloc(sizeof(int));
  int*   repRows = (int*)alloc((size_t)Nsup * sizeof(int));
  f16*   Q      = P;  // reuse: P fully consumed by fused_stats before gemm2
  (void)ws_size;

  // 1) f16 support matrix (padded) + norms; zero class/repair counters
  prep_kernel<<<Mpad / 4, 256, 0, stream>>>(z, W, C, Nsup, suph, norms, cls_cnt, repCnt);

  // 2) logit partials: P[kz] = f16(supports @ W^T over K-half kz)
  //    1D grid 640 = 8 xcd * 5 txPerXcd * 8 ty * 2 kz (XCD-pinned mapping)
  {
    const int txPerXcd = (Mpad / TM) / 8;   // 5
    gemm_f16<<<640, 256, 0, stream>>>(suph, suph, P, D, D / SPLITK, pStride1, Npad,
                                      txPerXcd);
  }

  // 3) fused stats: row merge/argmax/entropy -> repair -> accum, one
  //    cooperative launch with 2 grid syncs. Grid 512 = 2 blocks/CU,
  //    ~6.5 KB LDS, low VGPR -> co-residency margin >= 4x.
  {
    const f16* Pc = P;
    long ps = pStride1;
    int ldp = Npad, Cc = C, Ns = Nsup, Np = Npad;
    const float* zc = z;
    const float* Wc = W;
    float* entc = ent;
    int* rc = repCnt;
    int* rr = repRows;
    int* cc = cls_cnt;
    int* ci = cls_idx;
    const float* nc = norms;
    const int* kp = Kp;
    f16* whc = wh;
    void* args[] = {&Pc, &ps, &ldp, &Cc, &Ns, &Np, &zc, &Wc, &entc,
                    &rc, &rr, &cc, &ci, &nc, &kp, &whc};
    hipLaunchCooperativeKernel((void*)fused_stats, dim3(512), dim3(256), args, 0,
                               stream);
  }

  // 4) output partials: Q[kz] = f16(z @ weights^T over K-half kz)
  //    1D grid 512 = 8 * 4 * 8 * 2
  {
    const int txPerXcd = (B / TM) / 8;      // 4
    gemm_f16<<<512, 256, 0, stream>>>(suph + (size_t)C * D, wh, Q, D, D / SPLITK,
                                      pStride2, Npad, txPerXcd);
  }

  // 5) out = sum of 2 f16 partials (valid C cols only)
  reduce_out<<<B / 2, 256, 0, stream>>>(Q, pStride2, Npad, (float*)d_out, C);
}

// Round 5
// 197.499 us; speedup vs baseline: 1.4147x; 1.4147x over previous
//
#include <hip/hip_runtime.h>
#include <math.h>

// Problem shape (from reference setup_inputs): B=4096, D=2048, C=1000, N=C+B=5096.
#define D_DIM 2048
// |approx_logit - exact_logit| bound: fp16-MFMA dot (~0.013) + 2x f16 partial
// roundings (~0.004). Candidate containment needs GAP_TAU >= true bound.
#define GAP_TAU 0.03f
#define SPLITK 2
#define MAXLIST 1024
#define BK 64

typedef _Float16 f16;
typedef f16 f16x8 __attribute__((ext_vector_type(8)));
typedef f16 f16x4 __attribute__((ext_vector_type(4)));
typedef float f32x4 __attribute__((ext_vector_type(4)));
typedef float f32x16 __attribute__((ext_vector_type(16)));

__device__ __forceinline__ const float* support_row(int i, const float* __restrict__ W,
                                                    const float* __restrict__ z, int C) {
  return (i < C) ? (W + (size_t)i * D_DIM) : (z + (size_t)(i - C) * D_DIM);
}

// async global->LDS, 16B per lane. LDS dest = wave-uniform base + lane*16.
__device__ __forceinline__ void async_ld16(const f16* g, f16* l) {
  __builtin_amdgcn_global_load_lds((const __attribute__((address_space(1))) void*)g,
                                   (__attribute__((address_space(3))) void*)l, 16, 0, 0);
}

// ---------------------------------------------------------------------------
// prep: suph[i][:] = f16(support_row(i)) (zeros for pad rows); norms[i] = ||row||.
// One wave per row (4 rows/block), shuffle-only reduction.
// Also zeroes cls_cnt[0..C) and *repCnt (consumed after row_stats_fast).
// ---------------------------------------------------------------------------
__global__ __launch_bounds__(256) void prep_kernel(const float* __restrict__ z,
                                                   const float* __restrict__ W,
                                                   int C, int Nsup,
                                                   f16* __restrict__ suph,
                                                   float* __restrict__ norms,
                                                   int* __restrict__ cls_cnt,
                                                   int* __restrict__ repCnt) {
  if (blockIdx.x * 256 <= (unsigned)C) {
    const int gi = blockIdx.x * 256 + threadIdx.x;
    if (gi < C) cls_cnt[gi] = 0;
    if (gi == C) *repCnt = 0;
  }
  const int wave = threadIdx.x >> 6;
  const int lane = threadIdx.x & 63;
  const int i = blockIdx.x * 4 + wave;
  f16* dst = suph + (size_t)i * D_DIM;
  if (i >= Nsup) {
    f16x8 zz = {0, 0, 0, 0, 0, 0, 0, 0};
#pragma unroll
    for (int p = 0; p < 4; p++) *(f16x8*)(dst + p * 512 + lane * 8) = zz;
    return;
  }
  const float* src = support_row(i, W, z, C);
  float ss = 0.f;
#pragma unroll
  for (int p = 0; p < 4; p++) {
    const int off = p * 512 + lane * 8;
    const float4 a = *(const float4*)(src + off);
    const float4 b = *(const float4*)(src + off + 4);
    f16x8 v;
    v[0] = (f16)a.x; v[1] = (f16)a.y; v[2] = (f16)a.z; v[3] = (f16)a.w;
    v[4] = (f16)b.x; v[5] = (f16)b.y; v[6] = (f16)b.z; v[7] = (f16)b.w;
    *(f16x8*)(dst + off) = v;
    ss = fmaf(a.x, a.x, ss); ss = fmaf(a.y, a.y, ss);
    ss = fmaf(a.z, a.z, ss); ss = fmaf(a.w, a.w, ss);
    ss = fmaf(b.x, b.x, ss); ss = fmaf(b.y, b.y, ss);
    ss = fmaf(b.z, b.z, ss); ss = fmaf(b.w, b.w, ss);
  }
#pragma unroll
  for (int s = 1; s < 64; s <<= 1) ss += __shfl_xor(ss, s);
  if (lane == 0) norms[i] = sqrtf(ss);
}

// ---------------------------------------------------------------------------
// gemm_pipe: fp16 MFMA GEMM, 256x256 tile, 8 waves (512 thr, 2x4), BK=64,
// split-K=2, double-buffered LDS (128 KB), depth-2 prefetch with RAW
// s_barrier + counted s_waitcnt vmcnt(8) (never a full drain in the loop).
// Per wave: 128x64 output = 4x2 MFMA 32x32x16, 4 k-steps per BK iter.
// Swizzle (proven rounds 0-3): physical 16B chunk p = g ^ (row&7) ->
// conflict-free ds_read_b128; staging lane-sequential (global_load_lds).
// Mapping: l&3 = ty, (l>>2)&1 = kz, l>>3 = tx. XCD x <- l%8 = (ty,kz) pair,
// so each XCD's single B-panel (512 KB) stays L2-resident.
// Iter structure (hazard-traced):
//   reads ks01 -> MFMA ks01 -> reads ks23 -> lgkmcnt(0); s_barrier
//   -> STAGE(buf[cur], t+2) -> MFMA ks23 -> vmcnt(8); s_barrier -> cur^=1
// barrier1: all waves done reading buf[cur] before overwrite. vmcnt(8):
// own t+1 loads landed (t+2's 8 still in flight); barrier2 publishes.
// ---------------------------------------------------------------------------
__global__ __launch_bounds__(512, 2) void gemm_pipe(const f16* __restrict__ A,
                                                    const f16* __restrict__ B,
                                                    f16* __restrict__ P,
                                                    int K, int Ks, long partStride,
                                                    int ldc) {
  __shared__ __align__(16) f16 lds[4][16384];  // A0,B0,A1,B1: 32 KB each

  const int l = blockIdx.x;
  const int ty = l & 3;
  const int kz = (l >> 2) & 1;
  const int tx = l >> 3;
  const int row0 = tx * 256;
  const int col0 = ty * 256;
  const int kbase = kz * Ks;

  const int tid = threadIdx.x;
  const int wave = tid >> 6;
  const int lane = tid & 63;
  const int lr32 = lane & 31;    // row within 32-block (A) / col (B, C/D)
  const int half = lane >> 5;    // k-chunk half selector
  const int wr = (wave >> 2) * 128;   // 2 wave-rows
  const int wc = (wave & 3) * 64;     // 4 wave-cols

  // staging: 2048 16B-chunks per 256x64 tile -> 4 instr/thread for A, 4 for B.
  // chunk id i = (row<<3)|p; source global chunk g = p ^ (row&7).
  const f16* ag[4];
  const f16* bg[4];
  int loff[4];
#pragma unroll
  for (int s = 0; s < 4; s++) {
    const int i = (s * 8 + wave) * 64 + lane;   // 0..2047 == LDS chunk id
    const int row = i >> 3;
    const int g = (i & 7) ^ (row & 7);
    ag[s] = A + (size_t)(row0 + row) * K + kbase + g * 8;
    bg[s] = B + (size_t)(col0 + row) * K + kbase + g * 8;
    loff[s] = i * 8;   // f16 offset within buffer (16B per chunk)
  }

  // fragment offsets: k-step ks reads global chunk (ks*2+half) of row r at
  // physical chunk ((ks*2+half) ^ (r&7)).
  int aoff[4][4], boff[2][4];
#pragma unroll
  for (int mb = 0; mb < 4; mb++) {
    const int ra = wr + mb * 32 + lr32;
#pragma unroll
    for (int ks = 0; ks < 4; ks++)
      aoff[mb][ks] = ra * 64 + (((ks * 2 + half) ^ (ra & 7)) << 3);
  }
#pragma unroll
  for (int nb = 0; nb < 2; nb++) {
    const int rb = wc + nb * 32 + lr32;
#pragma unroll
    for (int ks = 0; ks < 4; ks++)
      boff[nb][ks] = rb * 64 + (((ks * 2 + half) ^ (rb & 7)) << 3);
  }

  f32x16 acc[4][2];
#pragma unroll
  for (int i = 0; i < 4; i++)
#pragma unroll
    for (int j = 0; j < 2; j++)
#pragma unroll
      for (int r = 0; r < 16; r++) acc[i][j][r] = 0.f;

  const int NT = Ks / BK;   // 16

  // prologue: stage tiles 0 and 1; wait tile 0 (oldest 8), keep 1 in flight
#pragma unroll
  for (int s = 0; s < 4; s++) {
    async_ld16(ag[s], &lds[0][loff[s]]);
    async_ld16(bg[s], &lds[1][loff[s]]);
  }
#pragma unroll
  for (int s = 0; s < 4; s++) {
    async_ld16(ag[s] + BK, &lds[2][loff[s]]);
    async_ld16(bg[s] + BK, &lds[3][loff[s]]);
  }
  asm volatile("s_waitcnt vmcnt(8)" ::: "memory");
  __builtin_amdgcn_sched_barrier(0);
  __builtin_amdgcn_s_barrier();

  int cur = 0;
#pragma unroll 1
  for (int t = 0; t < NT; ++t) {
    const f16* Ab = lds[cur * 2];
    const f16* Bb = lds[cur * 2 + 1];

    // ---- k-steps 0,1: read frags, compute ----
    f16x8 a0[4], a1[4], b0[2], b1[2];
#pragma unroll
    for (int mb = 0; mb < 4; mb++) {
      a0[mb] = *(const f16x8*)(Ab + aoff[mb][0]);
      a1[mb] = *(const f16x8*)(Ab + aoff[mb][1]);
    }
#pragma unroll
    for (int nb = 0; nb < 2; nb++) {
      b0[nb] = *(const f16x8*)(Bb + boff[nb][0]);
      b1[nb] = *(const f16x8*)(Bb + boff[nb][1]);
    }
#pragma unroll
    for (int mb = 0; mb < 4; mb++)
#pragma unroll
      for (int nb = 0; nb < 2; nb++)
        acc[mb][nb] = __builtin_amdgcn_mfma_f32_32x32x16_f16(a0[mb], b0[nb],
                                                             acc[mb][nb], 0, 0, 0);
#pragma unroll
    for (int mb = 0; mb < 4; mb++)
#pragma unroll
      for (int nb = 0; nb < 2; nb++)
        acc[mb][nb] = __builtin_amdgcn_mfma_f32_32x32x16_f16(a1[mb], b1[nb],
                                                             acc[mb][nb], 0, 0, 0);

    // ---- k-steps 2,3: read frags ----
    f16x8 a2[4], a3[4], b2[2], b3[2];
#pragma unroll
    for (int mb = 0; mb < 4; mb++) {
      a2[mb] = *(const f16x8*)(Ab + aoff[mb][2]);
      a3[mb] = *(const f16x8*)(Ab + aoff[mb][3]);
    }
#pragma unroll
    for (int nb = 0; nb < 2; nb++) {
      b2[nb] = *(const f16x8*)(Bb + boff[nb][2]);
      b3[nb] = *(const f16x8*)(Bb + boff[nb][3]);
    }

    // all reads of buf[cur] done -> safe to overwrite after barrier
    asm volatile("s_waitcnt lgkmcnt(0)" ::: "memory");
    __builtin_amdgcn_sched_barrier(0);
    __builtin_amdgcn_s_barrier();
    __builtin_amdgcn_sched_barrier(0);

    // prefetch tile t+2 into buf[cur] (overlaps MFMA ks23 + next iter ks01)
    if (t + 2 < NT) {
      f16* Al = lds[cur * 2];
      f16* Bl = lds[cur * 2 + 1];
      const int ko = (t + 2) * BK;
#pragma unroll
      for (int s = 0; s < 4; s++) {
        async_ld16(ag[s] + ko, Al + loff[s]);
        async_ld16(bg[s] + ko, Bl + loff[s]);
      }
    }

#pragma unroll
    for (int mb = 0; mb < 4; mb++)
#pragma unroll
      for (int nb = 0; nb < 2; nb++)
        acc[mb][nb] = __builtin_amdgcn_mfma_f32_32x32x16_f16(a2[mb], b2[nb],
                                                             acc[mb][nb], 0, 0, 0);
#pragma unroll
    for (int mb = 0; mb < 4; mb++)
#pragma unroll
      for (int nb = 0; nb < 2; nb++)
        acc[mb][nb] = __builtin_amdgcn_mfma_f32_32x32x16_f16(a3[mb], b3[nb],
                                                             acc[mb][nb], 0, 0, 0);

    if (t < NT - 1) {
      if (t + 2 < NT) {
        asm volatile("s_waitcnt vmcnt(8)" ::: "memory");   // t+1's loads landed
      } else {
        asm volatile("s_waitcnt vmcnt(0)" ::: "memory");   // drain for last tile
      }
      __builtin_amdgcn_sched_barrier(0);
      __builtin_amdgcn_s_barrier();
      __builtin_amdgcn_sched_barrier(0);
    }
    cur ^= 1;
  }

  // C/D 32x32 layout: col = lane&31, row = (reg&3) + 8*(reg>>2) + 4*(lane>>5)
  f16* out = P + (size_t)kz * partStride;
#pragma unroll
  for (int mb = 0; mb < 4; mb++)
#pragma unroll
    for (int reg = 0; reg < 16; reg++) {
      const int r = row0 + wr + mb * 32 + (reg & 3) + ((reg >> 2) << 3) + (half << 2);
#pragma unroll
      for (int nb = 0; nb < 2; nb++) {
        const int c = col0 + wc + nb * 32 + lr32;
        out[(size_t)r * ldc + c] = (f16)acc[mb][nb][reg];
      }
    }
}

// ---------------------------------------------------------------------------
// row_stats_fast: ONE WAVE per row, zero barriers. Lane owns 16 cols
// (lane*8..+7 and 512+lane*8..+7), coalesced f16x8 loads of both partials.
// Top-2/argmax + entropy via shfl_xor butterflies. Ambiguous rows go to a
// repair list; others bucket into per-class lists.
// ---------------------------------------------------------------------------
__global__ __launch_bounds__(256) void row_stats_fast(
    const f16* __restrict__ P, long partStride, int ldp, int Cc, int Nsup,
    float* __restrict__ ent, int* __restrict__ repCnt, int* __restrict__ repRows,
    int* __restrict__ cls_cnt, int* __restrict__ cls_idx) {
  const int wave = threadIdx.x >> 6;
  const int lane = threadIdx.x & 63;
  const int r = blockIdx.x * 4 + wave;
  if (r >= Nsup) return;

  const f16* base = P + (size_t)r * ldp + lane * 8;
  const f16x8 p0 = *(const f16x8*)(base);
  const f16x8 p1 = *(const f16x8*)(base + 512);
  const f16x8 q0 = *(const f16x8*)(base + partStride);
  const f16x8 q1 = *(const f16x8*)(base + partStride + 512);

  float v[16];
#pragma unroll
  for (int k = 0; k < 8; k++) v[k] = (float)p0[k] + (float)q0[k];
#pragma unroll
  for (int k = 0; k < 8; k++) v[8 + k] = (float)p1[k] + (float)q1[k];

  const int cbase = lane * 8;
#pragma unroll
  for (int k = 0; k < 16; k++) {
    const int col = (k < 8) ? (cbase + k) : (512 + cbase + k - 8);
    if (col >= Cc) v[k] = -3.0e38f;
  }

  // per-lane top-2 (+ lowest argmax idx; ascending col order within lane)
  float m1 = -3.0e38f, m2 = -3.0e38f;
  int i1 = 0x7fffffff;
#pragma unroll
  for (int k = 0; k < 16; k++) {
    const int col = (k < 8) ? (cbase + k) : (512 + cbase + k - 8);
    const float x = v[k];
    if (x > m1) { m2 = m1; m1 = x; i1 = col; }
    else if (x > m2) { m2 = x; }   // x==m1 lands here -> m2=m1 (gap 0)
  }
  // butterfly merge: all lanes converge to global (m1, m2, lowest i1)
#pragma unroll
  for (int s = 1; s < 64; s <<= 1) {
    const float om1 = __shfl_xor(m1, s);
    const float om2 = __shfl_xor(m2, s);
    const int oi1 = __shfl_xor(i1, s);
    if (om1 > m1) { m2 = fmaxf(m1, om2); m1 = om1; i1 = oi1; }
    else if (om1 < m1) { m2 = fmaxf(m2, om1); }
    else { i1 = min(i1, oi1); m2 = m1; }
  }

  // entropy rel. m1 (consumed only if a class exceeds K members)
  float s1 = 0.f, s2 = 0.f;
#pragma unroll
  for (int k = 0; k < 16; k++) {
    const int col = (k < 8) ? (cbase + k) : (512 + cbase + k - 8);
    if (col < Cc) {
      const float d = v[k] - m1;
      const float e = __expf(d);
      s1 += e;
      s2 = fmaf(d, e, s2);
    }
  }
#pragma unroll
  for (int s = 1; s < 64; s <<= 1) {
    s1 += __shfl_xor(s1, s);
    s2 += __shfl_xor(s2, s);
  }

  if (lane == 0) {
    ent[r] = logf(s1) - s2 / s1;
    if (m1 - m2 <= 2.0f * GAP_TAU) {
      const int p = atomicAdd(repCnt, 1);
      if (p < Nsup) repRows[p] = r;
    } else {
      const int p = atomicAdd(&cls_cnt[i1], 1);
      if (p < MAXLIST) cls_idx[(size_t)i1 * MAXLIST + p] = r;
    }
  }
}

// ---------------------------------------------------------------------------
// repair: one block per ambiguous row (strided over runtime count). Recomputes
// M1/M2 (exact comparisons -> same values as fast path), then the VERBATIM old
// candidate collection + exact fp32 block-dot code -> yhat bitwise-identical.
// Buckets the resolved class.
// ---------------------------------------------------------------------------
__global__ __launch_bounds__(256) void repair_kernel(
    const f16* __restrict__ P, long partStride, int ldp, int Cc,
    const float* __restrict__ z, const float* __restrict__ W,
    const int* __restrict__ repCnt, const int* __restrict__ repRows,
    int* __restrict__ cls_cnt, int* __restrict__ cls_idx) {
  const int t = threadIdx.x;
  const int wave = t >> 6;
  const int lane = t & 63;
  __shared__ float sm1[4], sm2[4];
  __shared__ float bc[2];
  __shared__ int cand[64];
  __shared__ int ncand;
  __shared__ float red[256];
  const int nrep = *repCnt;

  for (int q = blockIdx.x; q < nrep; q += gridDim.x) {
    const int r = repRows[q];
    const int c0 = t * 4;
    float v[4] = {0.f, 0.f, 0.f, 0.f};
#pragma unroll
    for (int kz = 0; kz < SPLITK; kz++) {
      const f16x4 p = *(const f16x4*)(P + (size_t)kz * partStride + (size_t)r * ldp + c0);
#pragma unroll
      for (int k = 0; k < 4; k++) v[k] += (float)p[k];
    }
#pragma unroll
    for (int k = 0; k < 4; k++)
      if (c0 + k >= Cc) v[k] = -3.0e38f;

    // top-2 values only (indices resolved by exact dots below)
    float m1 = -3.0e38f, m2 = -3.0e38f;
#pragma unroll
    for (int k = 0; k < 4; k++) {
      const float x = v[k];
      if (x > m1) { m2 = m1; m1 = x; }
      else if (x > m2) { m2 = x; }
    }
#pragma unroll
    for (int s = 1; s < 64; s <<= 1) {
      const float om1 = __shfl_xor(m1, s);
      const float om2 = __shfl_xor(m2, s);
      if (om1 > m1) { m2 = fmaxf(m1, om2); m1 = om1; }
      else if (om1 < m1) { m2 = fmaxf(m2, om1); }
      else { m2 = m1; }
    }
    if (lane == 0) { sm1[wave] = m1; sm2[wave] = m2; }
    __syncthreads();
    if (t == 0) {
      float M1 = sm1[0], M2 = sm2[0];
#pragma unroll
      for (int w = 1; w < 4; w++) {
        const float o1 = sm1[w], o2 = sm2[w];
        if (o1 > M1) { M2 = fmaxf(M1, o2); M1 = o1; }
        else if (o1 < M1) { M2 = fmaxf(M2, o1); }
        else { M2 = M1; }
      }
      bc[0] = M1; bc[1] = M2;
      ncand = 0;
    }
    __syncthreads();
    const float M1 = bc[0];
    const float thresh = M1 - 2.0f * GAP_TAU;
#pragma unroll
    for (int k = 0; k < 4; k++) {
      if (c0 + k < Cc && v[k] >= thresh) {
        const int p = atomicAdd(&ncand, 1);
        if (p < 64) cand[p] = c0 + k;
      }
    }
    __syncthreads();
    const bool overflow = (ncand > 64);
    const int nc = overflow ? Cc : ncand;
    const float* srow = support_row(r, W, z, Cc);
    float best = -3.0e38f;
    int bi = 0x7fffffff;
    for (int j = 0; j < nc; j++) {
      const int c = overflow ? j : cand[j];
      const float* wrow = W + (size_t)c * D_DIM;
      float s = 0.f;
      for (int d = t; d < D_DIM; d += 256) s = fmaf(srow[d], wrow[d], s);
      red[t] = s;
      __syncthreads();
      for (int k = 128; k > 0; k >>= 1) {
        if (t < k) red[t] += red[t + k];
        __syncthreads();
      }
      const float val = red[0];
      __syncthreads();
      if (val > best || (val == best && c < bi)) { best = val; bi = c; }
    }
    if (t == 0) {
      const int p = atomicAdd(&cls_cnt[bi], 1);
      if (p < MAXLIST) cls_idx[(size_t)bi * MAXLIST + p] = r;
    }
    __syncthreads();   // shared reuse across q iterations
  }
}

// ---------------------------------------------------------------------------
// accum: per class — read pre-bucketed member list, top-K by entropy if
// count > K (never in practice: mean ~5, K=100), sum normalized rows,
// column-normalize, write f16 weights row. Pad classes write zeros.
// ---------------------------------------------------------------------------
__global__ __launch_bounds__(256) void accum_kernel(
    const float* __restrict__ z, const float* __restrict__ W,
    int C, int Nsup,
    const int* __restrict__ cls_cnt, const int* __restrict__ cls_idx,
    const float* __restrict__ ent, const float* __restrict__ norms,
    const int* __restrict__ Kp, f16* __restrict__ wh) {
  const int c = blockIdx.x;
  const int t = threadIdx.x;
  f16* dst = wh + (size_t)c * D_DIM + t * 8;
  if (c >= C) {
    f16x8 zz = {0, 0, 0, 0, 0, 0, 0, 0};
    *(f16x8*)dst = zz;
    return;
  }

  __shared__ int slist[MAXLIST];
  __shared__ unsigned char sel[MAXLIST];
  __shared__ float red[256];
  const int cnt = cls_cnt[c];
  const int n = min(cnt, MAXLIST);
  const int* list = cls_idx + (size_t)c * MAXLIST;
  for (int j = t; j < n; j += 256) slist[j] = list[j];
  __syncthreads();
  const int K = *Kp;
  const bool all = (cnt <= K);
  if (!all) {
    for (int j = t; j < n; j += 256) {
      const int si = slist[j];
      const float ei = ent[si];
      int rank = 0;
      for (int l = 0; l < n; l++) {
        const int sl = slist[l];
        const float el = ent[sl];
        rank += (el < ei || (el == ei && sl < si)) ? 1 : 0;
      }
      sel[j] = (rank < K) ? 1 : 0;
    }
    __syncthreads();
  }

  float a[8];
#pragma unroll
  for (int q = 0; q < 8; q++) a[q] = 0.f;
  for (int j = 0; j < n; j++) {
    if (!all && !sel[j]) continue;
    const int si = slist[j];
    const float* row = support_row(si, W, z, C) + t * 8;
    const float inv = 1.0f / fmaxf(norms[si], 1e-12f);
    const float4 p0 = *(const float4*)row;
    const float4 p1 = *(const float4*)(row + 4);
    a[0] = fmaf(p0.x, inv, a[0]); a[1] = fmaf(p0.y, inv, a[1]);
    a[2] = fmaf(p0.z, inv, a[2]); a[3] = fmaf(p0.w, inv, a[3]);
    a[4] = fmaf(p1.x, inv, a[4]); a[5] = fmaf(p1.y, inv, a[5]);
    a[6] = fmaf(p1.z, inv, a[6]); a[7] = fmaf(p1.w, inv, a[7]);
  }

  float ss = 0.f;
#pragma unroll
  for (int q = 0; q < 8; q++) ss = fmaf(a[q], a[q], ss);
  red[t] = ss;
  __syncthreads();
  for (int k = 128; k > 0; k >>= 1) {
    if (t < k) red[t] += red[t + k];
    __syncthreads();
  }
  const float invn = 1.0f / fmaxf(sqrtf(red[0]), 1e-12f);
  f16x8 o;
#pragma unroll
  for (int q = 0; q < 8; q++) o[q] = (f16)(a[q] * invn);
  *(f16x8*)dst = o;
}

// ---------------------------------------------------------------------------
// reduce_out: out[r][c] = sum of 2 f16 partials, c < Ncols. Two rows per
// block; thread owns 8 cols (f16x8 loads, 2x float4 store).
// ---------------------------------------------------------------------------
__global__ __launch_bounds__(256) void reduce_out(const f16* __restrict__ Q,
                                                  long partStride, int ldq,
                                                  float* __restrict__ out, int Ncols) {
  const int r = blockIdx.x * 2 + (threadIdx.x >> 7);
  const int c0 = (threadIdx.x & 127) * 8;
  const f16* base = Q + (size_t)r * ldq + c0;
  const f16x8 p = *(const f16x8*)(base);
  const f16x8 q = *(const f16x8*)(base + partStride);
  float v[8];
#pragma unroll
  for (int k = 0; k < 8; k++) v[k] = (float)p[k] + (float)q[k];
  float* o = out + (size_t)r * Ncols + c0;
  if (c0 + 8 <= Ncols) {
    *(float4*)(o) = make_float4(v[0], v[1], v[2], v[3]);
    *(float4*)(o + 4) = make_float4(v[4], v[5], v[6], v[7]);
  } else {
#pragma unroll
    for (int k = 0; k < 8; k++)
      if (c0 + k < Ncols) o[k] = v[k];
  }
}

// ---------------------------------------------------------------------------
// Launch
// ---------------------------------------------------------------------------
extern "C" void kernel_launch(void* const* d_in, const int* in_sizes, int n_in,
                              void* d_out, int out_size, void* d_ws, size_t ws_size,
                              hipStream_t stream) {
  const float* z = (const float*)d_in[0];
  const float* W = (const float*)d_in[1];
  const int* Kp = (const int*)d_in[2];

  const int D = D_DIM;
  const int B = in_sizes[0] / D;   // 4096
  const int C = in_sizes[1] / D;   // 1000
  const int Nsup = C + B;          // 5096
  const int Mpad = (Nsup + 255) / 256 * 256;   // 5120
  const int Npad = 1024;                       // C padded to 256-multiple

  char* ws = (char*)d_ws;
  size_t off = 0;
  auto alloc = [&](size_t bytes) -> void* {
    void* p = ws + off;
    off += (bytes + 255) & ~(size_t)255;
    return p;
  };

  const long pStride1 = (long)Mpad * Npad;   // f16 elems per partial (gemm1)
  const long pStride2 = (long)B * Npad;      // f16 elems per partial (gemm2)

  f16*   suph   = (f16*)alloc((size_t)Mpad * D * sizeof(f16));            // ~21.0 MB
  f16*   wh     = (f16*)alloc((size_t)Npad * D * sizeof(f16));            // ~4.2 MB
  f16*   P      = (f16*)alloc((size_t)SPLITK * pStride1 * sizeof(f16));   // ~21.0 MB
  float* ent    = (float*)alloc((size_t)Nsup * sizeof(float));
  float* norms  = (float*)alloc((size_t)Nsup * sizeof(float));
  int*   cls_cnt = (int*)alloc((size_t)C * sizeof(int));
  int*   cls_idx = (int*)alloc((size_t)C * MAXLIST * sizeof(int));        // ~4.1 MB
  int*   repCnt = (int*)alloc(sizeof(int));
  int*   repRows = (int*)alloc((size_t)Nsup * sizeof(int));
  f16*   Q      = P;  // reuse: P fully consumed by row_stats/repair before gemm2
  (void)ws_size;

  // 1) f16 support matrix (padded) + norms; zero class/repair counters
  prep_kernel<<<Mpad / 4, 256, 0, stream>>>(z, W, C, Nsup, suph, norms, cls_cnt, repCnt);

  // 2) logit partials: P[kz] = f16(supports @ W^T over K-half kz)
  //    grid 160 = 20 tx * 4 ty * 2 kz; l%8 = (ty,kz) pins one B-panel per XCD
  gemm_pipe<<<(Mpad / 256) * 4 * 2, 512, 0, stream>>>(suph, suph, P, D, D / SPLITK,
                                                      pStride1, Npad);

  // 3) wave-per-row split-K merge + argmax/entropy; ambiguous -> repair list,
  //    resolved -> class buckets
  row_stats_fast<<<(Nsup + 3) / 4, 256, 0, stream>>>(P, pStride1, Npad, C, Nsup,
                                                     ent, repCnt, repRows,
                                                     cls_cnt, cls_idx);

  // 4) exact fp32 repair of ambiguous rows (dot order bitwise == round-3)
  repair_kernel<<<1024, 256, 0, stream>>>(P, pStride1, Npad, C, z, W,
                                          repCnt, repRows, cls_cnt, cls_idx);

  // 5) per-class gather/select/accumulate/normalize -> wh[Npad, D] f16
  accum_kernel<<<Npad, 256, 0, stream>>>(z, W, C, Nsup, cls_cnt, cls_idx,
                                         ent, norms, Kp, wh);

  // 6) output partials: Q[kz] = f16(z @ weights^T over K-half kz)
  //    grid 128 = 16 tx * 4 ty * 2 kz
  gemm_pipe<<<(B / 256) * 4 * 2, 512, 0, stream>>>(suph + (size_t)C * D, wh, Q, D,
                                                   D / SPLITK, pStride2, Npad);

  // 7) out = sum of 2 f16 partials (valid C cols only)
  reduce_out<<<B / 2, 256, 0, stream>>>(Q, pStride2, Npad, (float*)d_out, C);
}

// Round 6
// 181.739 us; speedup vs baseline: 1.5373x; 1.0867x over previous
//
#include <hip/hip_runtime.h>
#include <math.h>

// Problem shape (from reference setup_inputs): B=4096, D=2048, C=1000, N=C+B=5096.
#define D_DIM 2048
// |approx_logit - exact_logit| bound: fp16-MFMA dot (~0.013) + 2x f16 partial
// roundings (~0.004). Candidate containment needs GAP_TAU >= true bound.
#define GAP_TAU 0.03f
#define SPLITK 2
#define MAXLIST 1024

typedef _Float16 f16;
typedef f16 f16x8 __attribute__((ext_vector_type(8)));
typedef f16 f16x4 __attribute__((ext_vector_type(4)));
typedef float f32x4 __attribute__((ext_vector_type(4)));
typedef float f32x16 __attribute__((ext_vector_type(16)));

__device__ __forceinline__ const float* support_row(int i, const float* __restrict__ W,
                                                    const float* __restrict__ z, int C) {
  return (i < C) ? (W + (size_t)i * D_DIM) : (z + (size_t)(i - C) * D_DIM);
}

// async global->LDS, 16B per lane. LDS dest = wave-uniform base + lane*16.
__device__ __forceinline__ void async_ld16(const f16* g, f16* l) {
  __builtin_amdgcn_global_load_lds((const __attribute__((address_space(1))) void*)g,
                                   (__attribute__((address_space(3))) void*)l, 16, 0, 0);
}

// ---------------------------------------------------------------------------
// prep: suph[i][:] = f16(support_row(i)) (zeros for pad rows); norms[i] = ||row||.
// One wave per row (4 rows/block), shuffle-only reduction.
// Also zeroes cls_cnt[0..C) and *repCnt (consumed after row_stats_fast).
// ---------------------------------------------------------------------------
__global__ __launch_bounds__(256) void prep_kernel(const float* __restrict__ z,
                                                   const float* __restrict__ W,
                                                   int C, int Nsup,
                                                   f16* __restrict__ suph,
                                                   float* __restrict__ norms,
                                                   int* __restrict__ cls_cnt,
                                                   int* __restrict__ repCnt) {
  if (blockIdx.x * 256 <= (unsigned)C) {
    const int gi = blockIdx.x * 256 + threadIdx.x;
    if (gi < C) cls_cnt[gi] = 0;
    if (gi == C) *repCnt = 0;
  }
  const int wave = threadIdx.x >> 6;
  const int lane = threadIdx.x & 63;
  const int i = blockIdx.x * 4 + wave;
  f16* dst = suph + (size_t)i * D_DIM;
  if (i >= Nsup) {
    f16x8 zz = {0, 0, 0, 0, 0, 0, 0, 0};
#pragma unroll
    for (int p = 0; p < 4; p++) *(f16x8*)(dst + p * 512 + lane * 8) = zz;
    return;
  }
  const float* src = support_row(i, W, z, C);
  float ss = 0.f;
#pragma unroll
  for (int p = 0; p < 4; p++) {
    const int off = p * 512 + lane * 8;
    const float4 a = *(const float4*)(src + off);
    const float4 b = *(const float4*)(src + off + 4);
    f16x8 v;
    v[0] = (f16)a.x; v[1] = (f16)a.y; v[2] = (f16)a.z; v[3] = (f16)a.w;
    v[4] = (f16)b.x; v[5] = (f16)b.y; v[6] = (f16)b.z; v[7] = (f16)b.w;
    *(f16x8*)(dst + off) = v;
    ss = fmaf(a.x, a.x, ss); ss = fmaf(a.y, a.y, ss);
    ss = fmaf(a.z, a.z, ss); ss = fmaf(a.w, a.w, ss);
    ss = fmaf(b.x, b.x, ss); ss = fmaf(b.y, b.y, ss);
    ss = fmaf(b.z, b.z, ss); ss = fmaf(b.w, b.w, ss);
  }
#pragma unroll
  for (int s = 1; s < 64; s <<= 1) ss += __shfl_xor(ss, s);
  if (lane == 0) norms[i] = sqrtf(ss);
}

// ---------------------------------------------------------------------------
// fp16 MFMA GEMM, split-K=2, f16 partials, BK=64, XCD-pinned work mapping.
// 128x128 tile, 256 thr = 4 waves (2x2), wave = 64x64 = 2x2 MFMA 32x32x16,
// 4 k-steps of K=16 per BK=64 iter (16 iters at Ks=1024).
// Round-6 change: minimum 2-phase double-buffer (T3-lite). LDS 64 KB (2 bufs
// of As16K+Bs16K) -> still 2 blocks/CU. Per iter: issue STAGE(t+1 -> buf^1),
// compute tile t from buf[cur], ONE __syncthreads() (its builtin vmcnt(0)
// drain = the recipe's vmcnt(0);barrier). Staging latency hides under the
// 32 MFMA + 16 ds_read of tile t. Round-3's extra pre-compute barrier (which
// exposed the full global->LDS latency every iter) is gone.
// Hazards: buf^1's last reads were consumed by MFMAs before the end-of-(t-1)
// barrier -> safe to overwrite at iter t. End-of-t barrier drains each wave's
// own vmcnt -> staged tile t+1 visible to all waves at iter t+1.
// Swizzle (proven 0-conflict, rounds 0-3): physical chunk p = g ^ (row&7).
// C/D 32x32 layout: col = lane&31, row = (reg&3) + 8*(reg>>2) + 4*(lane>>5).
// Fragment math, MFMA order bit-identical to round 3 -> same partials.
// ---------------------------------------------------------------------------
#define TM 128
#define TN 128
#define BK 64

__global__ __launch_bounds__(256) void gemm_f16(const f16* __restrict__ A,
                                                const f16* __restrict__ B,
                                                f16* __restrict__ P,
                                                int K, int Ks, long partStride, int ldc,
                                                int txPerXcd) {
  // buf k: As at k*16384, Bs at k*16384 + 8192 (f16 elems). 64 KB total.
  __shared__ __align__(16) f16 sh[2 * 16384];

  const int l = blockIdx.x;
  const int xcd = l & 7;
  const int slot = l >> 3;
  const int tx = xcd + 8 * (slot % txPerXcd);
  const int rest = slot / txPerXcd;        // 0..15
  const int ty = rest & 7;
  const int kz = rest >> 3;
  const int row0 = tx * TM;
  const int col0 = ty * TN;
  const int kbase = kz * Ks;

  const int tid = threadIdx.x;
  const int wave = tid >> 6;
  const int lane = tid & 63;
  const int lr32 = lane & 31;    // row within 32-block (A) / col (B, C/D)
  const int half = lane >> 5;    // k-chunk half selector
  const int wr = (wave >> 1) * 64;
  const int wc = (wave & 1) * 64;

  // staging: 1024 16B-chunks per tile -> 4 instr/thread for A, 4 for B.
  // chunk id i = (row<<3)|p; source global chunk g = p ^ (row&7).
  const f16* ag[4];
  const f16* bg[4];
  int aloff[4], bloff[4];
#pragma unroll
  for (int s = 0; s < 4; s++) {
    const int i = (wave * 4 + s) * 64 + lane;   // == LDS chunk id (staging contract)
    const int row = i >> 3;
    const int cg = (i & 7) ^ (row & 7);
    ag[s] = A + (size_t)(row0 + row) * K + kbase + cg * 8;
    bg[s] = B + (size_t)(col0 + row) * K + kbase + cg * 8;
    aloff[s] = (wave * 4 + s) * 512;          // within As of a buffer
    bloff[s] = 8192 + (wave * 4 + s) * 512;   // within Bs of a buffer
  }

  // fragment offsets: for k-step s (K=16), lane reads global chunk
  // (s*2 + half) of row r at physical chunk ((s*2+half) ^ (r&7)).
  // boff includes the +8192 Bs base.
  int aoff[2][4], boff[2][4];
#pragma unroll
  for (int b = 0; b < 2; b++) {
#pragma unroll
    for (int s = 0; s < 4; s++) {
      const int ra = wr + b * 32 + lr32;
      aoff[b][s] = ra * 64 + (((s * 2 + half) ^ (ra & 7)) << 3);
      const int rb = wc + b * 32 + lr32;
      boff[b][s] = 8192 + rb * 64 + (((s * 2 + half) ^ (rb & 7)) << 3);
    }
  }

  f32x16 acc[2][2];
#pragma unroll
  for (int i = 0; i < 2; i++)
#pragma unroll
    for (int j = 0; j < 2; j++)
#pragma unroll
      for (int r = 0; r < 16; r++) acc[i][j][r] = 0.f;

  const int NT = Ks / BK;   // 16

  // prologue: stage tile 0 into buf 0
#pragma unroll
  for (int s = 0; s < 4; s++) {
    async_ld16(ag[s], sh + aloff[s]);
    async_ld16(bg[s], sh + bloff[s]);
  }
  __syncthreads();

  int cur = 0;
#pragma unroll 1
  for (int t = 0; t < NT; ++t) {
    // issue next-tile staging into the other buffer (overlaps this tile's
    // ds_reads + MFMAs; drained by the end-of-iter barrier)
    if (t + 1 < NT) {
      const int nb = (cur ^ 1) * 16384;
      const int ko = (t + 1) * BK;
#pragma unroll
      for (int s = 0; s < 4; s++) {
        async_ld16(ag[s] + ko, sh + nb + aloff[s]);
        async_ld16(bg[s] + ko, sh + nb + bloff[s]);
      }
    }

    const f16* buf = sh + cur * 16384;
#pragma unroll
    for (int s = 0; s < 2; s++) {
      f16x8 af[4], bf[4];
#pragma unroll
      for (int i = 0; i < 4; i++) af[i] = *(const f16x8*)(buf + aoff[i & 1][s * 2 + (i >> 1)]);
#pragma unroll
      for (int i = 0; i < 4; i++) bf[i] = *(const f16x8*)(buf + boff[i & 1][s * 2 + (i >> 1)]);
      // af[0]=A(b0,ks0') af[1]=A(b1,ks0') af[2]=A(b0,ks1') af[3]=A(b1,ks1')
      // same ordering as round 3's two half-iters: ks pair (s*2, s*2+1)
      acc[0][0] = __builtin_amdgcn_mfma_f32_32x32x16_f16(af[0], bf[0], acc[0][0], 0, 0, 0);
      acc[0][1] = __builtin_amdgcn_mfma_f32_32x32x16_f16(af[0], bf[1], acc[0][1], 0, 0, 0);
      acc[1][0] = __builtin_amdgcn_mfma_f32_32x32x16_f16(af[1], bf[0], acc[1][0], 0, 0, 0);
      acc[1][1] = __builtin_amdgcn_mfma_f32_32x32x16_f16(af[1], bf[1], acc[1][1], 0, 0, 0);
      acc[0][0] = __builtin_amdgcn_mfma_f32_32x32x16_f16(af[2], bf[2], acc[0][0], 0, 0, 0);
      acc[0][1] = __builtin_amdgcn_mfma_f32_32x32x16_f16(af[2], bf[3], acc[0][1], 0, 0, 0);
      acc[1][0] = __builtin_amdgcn_mfma_f32_32x32x16_f16(af[3], bf[2], acc[1][0], 0, 0, 0);
      acc[1][1] = __builtin_amdgcn_mfma_f32_32x32x16_f16(af[3], bf[3], acc[1][1], 0, 0, 0);
    }
    __syncthreads();   // drains own vmcnt (staged t+1 lands) + publishes buf free
    cur ^= 1;
  }

  f16* out = P + (size_t)kz * partStride;
#pragma unroll
  for (int bi = 0; bi < 2; bi++)
#pragma unroll
    for (int reg = 0; reg < 16; reg++) {
      const int r = row0 + wr + bi * 32 + (reg & 3) + ((reg >> 2) << 3) + (half << 2);
#pragma unroll
      for (int bj = 0; bj < 2; bj++) {
        const int c = col0 + wc + bj * 32 + lr32;
        out[(size_t)r * ldc + c] = (f16)acc[bi][bj][reg];
      }
    }
}

// ---------------------------------------------------------------------------
// row_stats_fast: ONE WAVE per row, zero barriers. Lane owns 16 cols
// (lane*8..+7 and 512+lane*8..+7), coalesced f16x8 loads of both partials.
// Top-2/argmax + entropy via shfl_xor butterflies. Ambiguous rows go to a
// repair list; others bucket into per-class lists.
// ---------------------------------------------------------------------------
__global__ __launch_bounds__(256) void row_stats_fast(
    const f16* __restrict__ P, long partStride, int ldp, int Cc, int Nsup,
    float* __restrict__ ent, int* __restrict__ repCnt, int* __restrict__ repRows,
    int* __restrict__ cls_cnt, int* __restrict__ cls_idx) {
  const int wave = threadIdx.x >> 6;
  const int lane = threadIdx.x & 63;
  const int r = blockIdx.x * 4 + wave;
  if (r >= Nsup) return;

  const f16* base = P + (size_t)r * ldp + lane * 8;
  const f16x8 p0 = *(const f16x8*)(base);
  const f16x8 p1 = *(const f16x8*)(base + 512);
  const f16x8 q0 = *(const f16x8*)(base + partStride);
  const f16x8 q1 = *(const f16x8*)(base + partStride + 512);

  float v[16];
#pragma unroll
  for (int k = 0; k < 8; k++) v[k] = (float)p0[k] + (float)q0[k];
#pragma unroll
  for (int k = 0; k < 8; k++) v[8 + k] = (float)p1[k] + (float)q1[k];

  const int cbase = lane * 8;
#pragma unroll
  for (int k = 0; k < 16; k++) {
    const int col = (k < 8) ? (cbase + k) : (512 + cbase + k - 8);
    if (col >= Cc) v[k] = -3.0e38f;
  }

  // per-lane top-2 (+ lowest argmax idx; ascending col order within lane)
  float m1 = -3.0e38f, m2 = -3.0e38f;
  int i1 = 0x7fffffff;
#pragma unroll
  for (int k = 0; k < 16; k++) {
    const int col = (k < 8) ? (cbase + k) : (512 + cbase + k - 8);
    const float x = v[k];
    if (x > m1) { m2 = m1; m1 = x; i1 = col; }
    else if (x > m2) { m2 = x; }   // x==m1 lands here -> m2=m1 (gap 0)
  }
  // butterfly merge: all lanes converge to global (m1, m2, lowest i1)
#pragma unroll
  for (int s = 1; s < 64; s <<= 1) {
    const float om1 = __shfl_xor(m1, s);
    const float om2 = __shfl_xor(m2, s);
    const int oi1 = __shfl_xor(i1, s);
    if (om1 > m1) { m2 = fmaxf(m1, om2); m1 = om1; i1 = oi1; }
    else if (om1 < m1) { m2 = fmaxf(m2, om1); }
    else { i1 = min(i1, oi1); m2 = m1; }
  }

  // entropy rel. m1 (consumed only if a class exceeds K members)
  float s1 = 0.f, s2 = 0.f;
#pragma unroll
  for (int k = 0; k < 16; k++) {
    const int col = (k < 8) ? (cbase + k) : (512 + cbase + k - 8);
    if (col < Cc) {
      const float d = v[k] - m1;
      const float e = __expf(d);
      s1 += e;
      s2 = fmaf(d, e, s2);
    }
  }
#pragma unroll
  for (int s = 1; s < 64; s <<= 1) {
    s1 += __shfl_xor(s1, s);
    s2 += __shfl_xor(s2, s);
  }

  if (lane == 0) {
    ent[r] = logf(s1) - s2 / s1;
    if (m1 - m2 <= 2.0f * GAP_TAU) {
      const int p = atomicAdd(repCnt, 1);
      if (p < Nsup) repRows[p] = r;
    } else {
      const int p = atomicAdd(&cls_cnt[i1], 1);
      if (p < MAXLIST) cls_idx[(size_t)i1 * MAXLIST + p] = r;
    }
  }
}

// ---------------------------------------------------------------------------
// repair: one block per ambiguous row (strided over runtime count). Recomputes
// M1/M2 (exact comparisons -> same values as fast path), then the VERBATIM old
// candidate collection + exact fp32 block-dot code -> yhat bitwise-identical.
// Buckets the resolved class.
// ---------------------------------------------------------------------------
__global__ __launch_bounds__(256) void repair_kernel(
    const f16* __restrict__ P, long partStride, int ldp, int Cc,
    const float* __restrict__ z, const float* __restrict__ W,
    const int* __restrict__ repCnt, const int* __restrict__ repRows,
    int* __restrict__ cls_cnt, int* __restrict__ cls_idx) {
  const int t = threadIdx.x;
  const int wave = t >> 6;
  const int lane = t & 63;
  __shared__ float sm1[4], sm2[4];
  __shared__ float bc[2];
  __shared__ int cand[64];
  __shared__ int ncand;
  __shared__ float red[256];
  const int nrep = *repCnt;

  for (int q = blockIdx.x; q < nrep; q += gridDim.x) {
    const int r = repRows[q];
    const int c0 = t * 4;
    float v[4] = {0.f, 0.f, 0.f, 0.f};
#pragma unroll
    for (int kz = 0; kz < SPLITK; kz++) {
      const f16x4 p = *(const f16x4*)(P + (size_t)kz * partStride + (size_t)r * ldp + c0);
#pragma unroll
      for (int k = 0; k < 4; k++) v[k] += (float)p[k];
    }
#pragma unroll
    for (int k = 0; k < 4; k++)
      if (c0 + k >= Cc) v[k] = -3.0e38f;

    // top-2 values only (indices resolved by exact dots below)
    float m1 = -3.0e38f, m2 = -3.0e38f;
#pragma unroll
    for (int k = 0; k < 4; k++) {
      const float x = v[k];
      if (x > m1) { m2 = m1; m1 = x; }
      else if (x > m2) { m2 = x; }
    }
#pragma unroll
    for (int s = 1; s < 64; s <<= 1) {
      const float om1 = __shfl_xor(m1, s);
      const float om2 = __shfl_xor(m2, s);
      if (om1 > m1) { m2 = fmaxf(m1, om2); m1 = om1; }
      else if (om1 < m1) { m2 = fmaxf(m2, om1); }
      else { m2 = m1; }
    }
    if (lane == 0) { sm1[wave] = m1; sm2[wave] = m2; }
    __syncthreads();
    if (t == 0) {
      float M1 = sm1[0], M2 = sm2[0];
#pragma unroll
      for (int w = 1; w < 4; w++) {
        const float o1 = sm1[w], o2 = sm2[w];
        if (o1 > M1) { M2 = fmaxf(M1, o2); M1 = o1; }
        else if (o1 < M1) { M2 = fmaxf(M2, o1); }
        else { M2 = M1; }
      }
      bc[0] = M1; bc[1] = M2;
      ncand = 0;
    }
    __syncthreads();
    const float M1 = bc[0];
    const float thresh = M1 - 2.0f * GAP_TAU;
#pragma unroll
    for (int k = 0; k < 4; k++) {
      if (c0 + k < Cc && v[k] >= thresh) {
        const int p = atomicAdd(&ncand, 1);
        if (p < 64) cand[p] = c0 + k;
      }
    }
    __syncthreads();
    const bool overflow = (ncand > 64);
    const int nc = overflow ? Cc : ncand;
    const float* srow = support_row(r, W, z, Cc);
    float best = -3.0e38f;
    int bi = 0x7fffffff;
    for (int j = 0; j < nc; j++) {
      const int c = overflow ? j : cand[j];
      const float* wrow = W + (size_t)c * D_DIM;
      float s = 0.f;
      for (int d = t; d < D_DIM; d += 256) s = fmaf(srow[d], wrow[d], s);
      red[t] = s;
      __syncthreads();
      for (int k = 128; k > 0; k >>= 1) {
        if (t < k) red[t] += red[t + k];
        __syncthreads();
      }
      const float val = red[0];
      __syncthreads();
      if (val > best || (val == best && c < bi)) { best = val; bi = c; }
    }
    if (t == 0) {
      const int p = atomicAdd(&cls_cnt[bi], 1);
      if (p < MAXLIST) cls_idx[(size_t)bi * MAXLIST + p] = r;
    }
    __syncthreads();   // shared reuse across q iterations
  }
}

// ---------------------------------------------------------------------------
// accum: per class — read pre-bucketed member list, top-K by entropy if
// count > K (never in practice: mean ~5, K=100), sum normalized rows,
// column-normalize, write f16 weights row. Pad classes write zeros.
// ---------------------------------------------------------------------------
__global__ __launch_bounds__(256) void accum_kernel(
    const float* __restrict__ z, const float* __restrict__ W,
    int C, int Nsup,
    const int* __restrict__ cls_cnt, const int* __restrict__ cls_idx,
    const float* __restrict__ ent, const float* __restrict__ norms,
    const int* __restrict__ Kp, f16* __restrict__ wh) {
  const int c = blockIdx.x;
  const int t = threadIdx.x;
  f16* dst = wh + (size_t)c * D_DIM + t * 8;
  if (c >= C) {
    f16x8 zz = {0, 0, 0, 0, 0, 0, 0, 0};
    *(f16x8*)dst = zz;
    return;
  }

  __shared__ int slist[MAXLIST];
  __shared__ unsigned char sel[MAXLIST];
  __shared__ float red[256];
  const int cnt = cls_cnt[c];
  const int n = min(cnt, MAXLIST);
  const int* list = cls_idx + (size_t)c * MAXLIST;
  for (int j = t; j < n; j += 256) slist[j] = list[j];
  __syncthreads();
  const int K = *Kp;
  const bool all = (cnt <= K);
  if (!all) {
    for (int j = t; j < n; j += 256) {
      const int si = slist[j];
      const float ei = ent[si];
      int rank = 0;
      for (int l = 0; l < n; l++) {
        const int sl = slist[l];
        const float el = ent[sl];
        rank += (el < ei || (el == ei && sl < si)) ? 1 : 0;
      }
      sel[j] = (rank < K) ? 1 : 0;
    }
    __syncthreads();
  }

  float a[8];
#pragma unroll
  for (int q = 0; q < 8; q++) a[q] = 0.f;
  for (int j = 0; j < n; j++) {
    if (!all && !sel[j]) continue;
    const int si = slist[j];
    const float* row = support_row(si, W, z, C) + t * 8;
    const float inv = 1.0f / fmaxf(norms[si], 1e-12f);
    const float4 p0 = *(const float4*)row;
    const float4 p1 = *(const float4*)(row + 4);
    a[0] = fmaf(p0.x, inv, a[0]); a[1] = fmaf(p0.y, inv, a[1]);
    a[2] = fmaf(p0.z, inv, a[2]); a[3] = fmaf(p0.w, inv, a[3]);
    a[4] = fmaf(p1.x, inv, a[4]); a[5] = fmaf(p1.y, inv, a[5]);
    a[6] = fmaf(p1.z, inv, a[6]); a[7] = fmaf(p1.w, inv, a[7]);
  }

  float ss = 0.f;
#pragma unroll
  for (int q = 0; q < 8; q++) ss = fmaf(a[q], a[q], ss);
  red[t] = ss;
  __syncthreads();
  for (int k = 128; k > 0; k >>= 1) {
    if (t < k) red[t] += red[t + k];
    __syncthreads();
  }
  const float invn = 1.0f / fmaxf(sqrtf(red[0]), 1e-12f);
  f16x8 o;
#pragma unroll
  for (int q = 0; q < 8; q++) o[q] = (f16)(a[q] * invn);
  *(f16x8*)dst = o;
}

// ---------------------------------------------------------------------------
// reduce_out: out[r][c] = sum of 2 f16 partials, c < Ncols. Two rows per
// block; thread owns 8 cols (f16x8 loads, 2x float4 store).
// ---------------------------------------------------------------------------
__global__ __launch_bounds__(256) void reduce_out(const f16* __restrict__ Q,
                                                  long partStride, int ldq,
                                                  float* __restrict__ out, int Ncols) {
  const int r = blockIdx.x * 2 + (threadIdx.x >> 7);
  const int c0 = (threadIdx.x & 127) * 8;
  const f16* base = Q + (size_t)r * ldq + c0;
  const f16x8 p = *(const f16x8*)(base);
  const f16x8 q = *(const f16x8*)(base + partStride);
  float v[8];
#pragma unroll
  for (int k = 0; k < 8; k++) v[k] = (float)p[k] + (float)q[k];
  float* o = out + (size_t)r * Ncols + c0;
  if (c0 + 8 <= Ncols) {
    *(float4*)(o) = make_float4(v[0], v[1], v[2], v[3]);
    *(float4*)(o + 4) = make_float4(v[4], v[5], v[6], v[7]);
  } else {
#pragma unroll
    for (int k = 0; k < 8; k++)
      if (c0 + k < Ncols) o[k] = v[k];
  }
}

// ---------------------------------------------------------------------------
// Launch
// ---------------------------------------------------------------------------
extern "C" void kernel_launch(void* const* d_in, const int* in_sizes, int n_in,
                              void* d_out, int out_size, void* d_ws, size_t ws_size,
                              hipStream_t stream) {
  const float* z = (const float*)d_in[0];
  const float* W = (const float*)d_in[1];
  const int* Kp = (const int*)d_in[2];

  const int D = D_DIM;
  const int B = in_sizes[0] / D;   // 4096
  const int C = in_sizes[1] / D;   // 1000
  const int Nsup = C + B;          // 5096
  const int Mpad = (Nsup + TM - 1) / TM * TM;  // 5120
  const int Npad = (C + TN - 1) / TN * TN;     // 1024

  char* ws = (char*)d_ws;
  size_t off = 0;
  auto alloc = [&](size_t bytes) -> void* {
    void* p = ws + off;
    off += (bytes + 255) & ~(size_t)255;
    return p;
  };

  const long pStride1 = (long)Mpad * Npad;   // f16 elems per partial (gemm1)
  const long pStride2 = (long)B * Npad;      // f16 elems per partial (gemm2)

  f16*   suph   = (f16*)alloc((size_t)Mpad * D * sizeof(f16));            // ~21.0 MB
  f16*   wh     = (f16*)alloc((size_t)Npad * D * sizeof(f16));            // ~4.2 MB
  f16*   P      = (f16*)alloc((size_t)SPLITK * pStride1 * sizeof(f16));   // ~21.0 MB
  float* ent    = (float*)alloc((size_t)Nsup * sizeof(float));
  float* norms  = (float*)alloc((size_t)Nsup * sizeof(float));
  int*   cls_cnt = (int*)alloc((size_t)C * sizeof(int));
  int*   cls_idx = (int*)alloc((size_t)C * MAXLIST * sizeof(int));        // ~4.1 MB
  int*   repCnt = (int*)alloc(sizeof(int));
  int*   repRows = (int*)alloc((size_t)Nsup * sizeof(int));
  f16*   Q      = P;  // reuse: P fully consumed by row_stats/repair before gemm2
  (void)ws_size;

  // 1) f16 support matrix (padded) + norms; zero class/repair counters
  prep_kernel<<<Mpad / 4, 256, 0, stream>>>(z, W, C, Nsup, suph, norms, cls_cnt, repCnt);

  // 2) logit partials: P[kz] = f16(supports @ W^T over K-half kz)
  //    1D grid 640 = 8 xcd * 5 txPerXcd * 8 ty * 2 kz (XCD-pinned mapping)
  {
    const int txPerXcd = (Mpad / TM) / 8;   // 5
    gemm_f16<<<640, 256, 0, stream>>>(suph, suph, P, D, D / SPLITK, pStride1, Npad,
                                      txPerXcd);
  }

  // 3) wave-per-row split-K merge + argmax/entropy; ambiguous -> repair list,
  //    resolved -> class buckets
  row_stats_fast<<<(Nsup + 3) / 4, 256, 0, stream>>>(P, pStride1, Npad, C, Nsup,
                                                     ent, repCnt, repRows,
                                                     cls_cnt, cls_idx);

  // 4) exact fp32 repair of ambiguous rows (dot order bitwise == round-3)
  repair_kernel<<<1024, 256, 0, stream>>>(P, pStride1, Npad, C, z, W,
                                          repCnt, repRows, cls_cnt, cls_idx);

  // 5) per-class gather/select/accumulate/normalize -> wh[Npad, D] f16
  accum_kernel<<<Npad, 256, 0, stream>>>(z, W, C, Nsup, cls_cnt, cls_idx,
                                         ent, norms, Kp, wh);

  // 6) output partials: Q[kz] = f16(z @ weights^T over K-half kz)
  //    1D grid 512 = 8 * 4 * 8 * 2
  {
    const int txPerXcd = (B / TM) / 8;      // 4
    gemm_f16<<<512, 256, 0, stream>>>(suph + (size_t)C * D, wh, Q, D, D / SPLITK,
                                      pStride2, Npad, txPerXcd);
  }

  // 7) out = sum of 2 f16 partials (valid C cols only)
  reduce_out<<<B / 2, 256, 0, stream>>>(Q, pStride2, Npad, (float*)d_out, C);
}